// Round 7
// baseline (27.202 us; speedup 1.0000x reference)
//
#include <hip/hip_runtime.h>
#include <math.h>

typedef __attribute__((ext_vector_type(8))) short bf16x8;
typedef __attribute__((ext_vector_type(4))) float f32x4;

#define T_TOT 16384
#define E_ 256
#define FF_ 1024
#define NQ 10
#define TB 64
#define CH 256           // f per chunk
#define NCHUNK (FF_ / CH)
#define HGRAN (TB * CH)  // shorts per hs buffer (16384 = 32 KiB)

__device__ __forceinline__ unsigned short f2bf(float f) {
    unsigned u = __builtin_bit_cast(unsigned, f);
    u = (u + 0x7FFFu + ((u >> 16) & 1u)) >> 16;
    return (unsigned short)u;
}

// ---------------------------------------------------------------------------
// Prep (coalesced): bf16 MFMA B-fragments for w2 and w1^T.
// ---------------------------------------------------------------------------
__global__ __launch_bounds__(256) void ffq_prep(
    const float* __restrict__ w2, const float* __restrict__ w1,
    uint4* __restrict__ w2f, uint4* __restrict__ w1f)
{
    int id = blockIdx.x * 256 + threadIdx.x;
    if (id < 32768) {
        int n  = id >> 7;
        int k0 = (id & 127) * 8;
        const float4* s = (const float4*)(w2 + (size_t)n * FF_ + k0);
        float4 a = s[0], b = s[1];
        uint4 v;
        v.x = f2bf(a.x) | ((unsigned)f2bf(a.y) << 16);
        v.y = f2bf(a.z) | ((unsigned)f2bf(a.w) << 16);
        v.z = f2bf(b.x) | ((unsigned)f2bf(b.y) << 16);
        v.w = f2bf(b.z) | ((unsigned)f2bf(b.w) << 16);
        int idx = ((k0 >> 5) * 16 + (n >> 4)) * 64 + ((k0 >> 3) & 3) * 16 + (n & 15);
        w2f[idx] = v;
    } else if (id < 32768 + 4096) {
        int id2 = id - 32768;
        int l = id2 & 63, nt = id2 >> 6;
        int n = nt * 16 + (l & 15);
        int g = l >> 4;
        unsigned short o[8];
#pragma unroll
        for (int j = 0; j < 8; ++j) {
            int k = g * 8 + j;
            o[j] = (k < NQ) ? f2bf(w1[n * NQ + k]) : (unsigned short)0;
        }
        uint4 v;
        v.x = o[0] | ((unsigned)o[1] << 16);
        v.y = o[2] | ((unsigned)o[3] << 16);
        v.z = o[4] | ((unsigned)o[5] << 16);
        v.w = o[6] | ((unsigned)o[7] << 16);
        w1f[id2] = v;
    }
}

// ---------------------------------------------------------------------------
// Fused kernel v5 (split-K waves):
//  - grid 512 = 256 token-tiles x 2 col-halves; block = 64 tok x 128 cols.
//  - 8 waves = 2 K-groups (wk) x 4 col-pairs (wc). Wave: 64 tok x 32 cols,
//    half of each chunk's kk range. A-LDS reads/MFMA = 0.5 (was 1.0).
//  - hs double-buffered; 1 barrier/chunk; B depth-1 register prefetch.
//  - final split-K reduce through LDS (stride-33, conflict-free), wk=0 stores.
// ---------------------------------------------------------------------------
__global__ __launch_bounds__(512, 4) void ffq_mfma(
    const float* __restrict__ x, const float* __restrict__ theta,
    const float* __restrict__ b1, const float* __restrict__ b2,
    const bf16x8* __restrict__ w1f, const bf16x8* __restrict__ w2f,
    float* __restrict__ out)
{
    __shared__ unsigned short q_s[4 * 64 * 8];      // 4 KiB
    __shared__ unsigned short hs[2 * HGRAN];        // 64 KiB (double buffer)

    const int tid  = threadIdx.x;
    const int l    = tid & 63;
    const int wv   = tid >> 6;           // 0..7
    const int lr   = l & 15;
    const int g    = l >> 4;             // 0..3
    const int wk   = wv >> 2;            // K-half 0/1
    const int wc   = wv & 3;             // col-pair 0..3
    const int chb  = blockIdx.x & 1;     // col half 0/1
    const int tb   = (blockIdx.x >> 1) * TB;
    const int nc0  = chb * 8 + wc * 2;   // global col-tiles
    const int nc1  = nc0 + 1;

    // ---- Phase 0: threads 0..63 compute q, write B-frag granules ----
    if (tid < TB) {
        const int t = tb + tid;
        float xv[NQ];
        {
            float4 a = *(const float4*)(x + (size_t)t * E_);
            float4 b = *(const float4*)(x + (size_t)t * E_ + 4);
            float2 c = *(const float2*)(x + (size_t)t * E_ + 8);
            xv[0]=a.x; xv[1]=a.y; xv[2]=a.z; xv[3]=a.w;
            xv[4]=b.x; xv[5]=b.y; xv[6]=b.z; xv[7]=b.w;
            xv[8]=c.x; xv[9]=c.y;
        }
        float mm[NQ];
#pragma unroll
        for (int w = 0; w < NQ; ++w) mm[w] = cosf(theta[w]) * cosf(xv[w]);
        float qv[NQ];
        {
            float p = mm[0];
#pragma unroll
            for (int w = 1; w < NQ; ++w) { p *= mm[w]; qv[w] = p; }
            float p0 = mm[1];
#pragma unroll
            for (int w = 2; w < NQ; ++w) p0 *= mm[w];
            qv[0] = p0;
        }
        unsigned short qb[10];
#pragma unroll
        for (int k = 0; k < NQ; ++k) qb[k] = f2bf(qv[k]);
        uint4 s0, s1;
        s0.x = qb[0] | ((unsigned)qb[1] << 16);
        s0.y = qb[2] | ((unsigned)qb[3] << 16);
        s0.z = qb[4] | ((unsigned)qb[5] << 16);
        s0.w = qb[6] | ((unsigned)qb[7] << 16);
        s1.x = qb[8] | ((unsigned)qb[9] << 16);
        s1.y = 0; s1.z = 0; s1.w = 0;
        int tt = tid >> 4, r = tid & 15;
        uint4* base = (uint4*)q_s + tt * 64;
        base[r]      = s0;
        base[16 + r] = s1;
        base[32 + r] = make_uint4(0, 0, 0, 0);
        base[48 + r] = make_uint4(0, 0, 0, 0);
    }
    __syncthreads();

    bf16x8 qf[4];
#pragma unroll
    for (int tt = 0; tt < 4; ++tt) qf[tt] = ((const bf16x8*)q_s)[tt * 64 + l];

    f32x4 acc[4][2];
#pragma unroll
    for (int tt = 0; tt < 4; ++tt)
#pragma unroll
        for (int nn = 0; nn < 2; ++nn) acc[tt][nn] = (f32x4){0.f,0.f,0.f,0.f};

    // ---- h-phase macro (chunk cc -> buffer hdst); all 8 waves, by wv ----
#define H_PHASE(cc, hdst)                                                      \
    {                                                                          \
        _Pragma("unroll")                                                      \
        for (int fi = 0; fi < 2; ++fi) {                                       \
            const int ftl = wv * 2 + fi;                                       \
            const int ntg = (cc) * 16 + ftl;                                   \
            bf16x8 wf = w1f[ntg * 64 + l];                                     \
            const int f0  = ntg * 16 + g * 4;                                  \
            float4 bb = *(const float4*)(b1 + f0);                             \
            const int fl   = ftl * 16 + g * 4;                                 \
            const int sl   = (fl & 31) >> 3;                                   \
            const int gran = (fl >> 5) * 64 + lr + 16 * sl;                    \
            _Pragma("unroll")                                                  \
            for (int tt = 0; tt < 4; ++tt) {                                   \
                f32x4 d = {0.f, 0.f, 0.f, 0.f};                                \
                d = __builtin_amdgcn_mfma_f32_16x16x32_bf16(                   \
                        wf, qf[tt], d, 0, 0, 0);                               \
                unsigned p0 = f2bf(fmaxf(d[0] + bb.x, 0.f))                    \
                            | ((unsigned)f2bf(fmaxf(d[1] + bb.y, 0.f)) << 16); \
                unsigned p1 = f2bf(fmaxf(d[2] + bb.z, 0.f))                    \
                            | ((unsigned)f2bf(fmaxf(d[3] + bb.w, 0.f)) << 16); \
                unsigned byteoff = (unsigned)(tt * 512 + gran) * 16u           \
                                 + (unsigned)(fl & 7) * 2u;                    \
                *(uint2*)((char*)(hdst) + byteoff) = make_uint2(p0, p1);       \
            }                                                                  \
        }                                                                      \
    }

    // ---- prologue: chunk 0 h-phase into buf0; init B prefetch ----
    H_PHASE(0, hs)
    bf16x8 bc0 = w2f[((wk * 4) * 16 + nc0) * 64 + l];
    bf16x8 bc1 = w2f[((wk * 4) * 16 + nc1) * 64 + l];
    __syncthreads();

    for (int c = 0; c < NCHUNK; ++c) {
        const unsigned short* hcur = hs + (c & 1) * HGRAN;
        unsigned short*       hnxt = hs + ((c & 1) ^ 1) * HGRAN;

        // ---- out-phase: 4 kkl steps of this wave's K-half ----
#pragma unroll
        for (int j = 0; j < 4; ++j) {
            const int kkl = wk * 4 + j;
            const int kk  = c * 8 + kkl;
            const int kkn = (j < 3) ? kk + 1
                          : ((c < NCHUNK - 1) ? kk + 5 : kk);
            bf16x8 bn0 = w2f[(kkn * 16 + nc0) * 64 + l];
            bf16x8 bn1 = w2f[(kkn * 16 + nc1) * 64 + l];
            bf16x8 af[4];
#pragma unroll
            for (int tt = 0; tt < 4; ++tt)
                af[tt] = ((const bf16x8*)hcur)[(tt * 8 + kkl) * 64 + l];
#pragma unroll
            for (int tt = 0; tt < 4; ++tt)
                acc[tt][0] = __builtin_amdgcn_mfma_f32_16x16x32_bf16(
                    af[tt], bc0, acc[tt][0], 0, 0, 0);
#pragma unroll
            for (int tt = 0; tt < 4; ++tt)
                acc[tt][1] = __builtin_amdgcn_mfma_f32_16x16x32_bf16(
                    af[tt], bc1, acc[tt][1], 0, 0, 0);
            bc0 = bn0; bc1 = bn1;
        }

        // ---- h-phase for chunk c+1 (overlaps out-phase latency) ----
        if (c < NCHUNK - 1) {
            H_PHASE(c + 1, hnxt)
        }
        __syncthreads();
    }
#undef H_PHASE

    // ---- split-K reduce via LDS (stride 33 -> conflict-free banks) ----
    float* pbuf = (float*)hs;
    const int idx = wc * 64 + l;     // 0..255, same for wk=0/1 partners
    if (wk == 1) {
#pragma unroll
        for (int tt = 0; tt < 4; ++tt)
#pragma unroll
            for (int nn = 0; nn < 2; ++nn)
#pragma unroll
                for (int r = 0; r < 4; ++r)
                    pbuf[idx * 33 + (tt * 2 + nn) * 4 + r] = acc[tt][nn][r];
    }
    __syncthreads();
    if (wk == 0) {
#pragma unroll
        for (int tt = 0; tt < 4; ++tt)
#pragma unroll
            for (int nn = 0; nn < 2; ++nn)
#pragma unroll
                for (int r = 0; r < 4; ++r)
                    acc[tt][nn][r] += pbuf[idx * 33 + (tt * 2 + nn) * 4 + r];

        // ---- epilogue: + b2, store fp32 ----
#pragma unroll
        for (int nn = 0; nn < 2; ++nn) {
            const int col = (nc0 + nn) * 16 + lr;
            const float bbv = b2[col];
#pragma unroll
            for (int tt = 0; tt < 4; ++tt) {
#pragma unroll
                for (int r = 0; r < 4; ++r) {
                    int tr = tb + tt * 16 + g * 4 + r;
                    out[(size_t)tr * E_ + col] = acc[tt][nn][r] + bbv;
                }
            }
        }
    }
}

extern "C" void kernel_launch(void* const* d_in, const int* in_sizes, int n_in,
                              void* d_out, int out_size, void* d_ws, size_t ws_size,
                              hipStream_t stream) {
    const float* x     = (const float*)d_in[0];
    const float* theta = (const float*)d_in[1];
    const float* w1    = (const float*)d_in[2];
    const float* b1    = (const float*)d_in[3];
    const float* w2    = (const float*)d_in[4];
    const float* b2    = (const float*)d_in[5];
    float* out = (float*)d_out;

    uint4* w2f = (uint4*)d_ws;                          // 512 KiB
    uint4* w1f = (uint4*)((char*)d_ws + 512 * 1024);    // 64 KiB

    hipLaunchKernelGGL(ffq_prep, dim3(144), dim3(256), 0, stream,
                       w2, w1, w2f, w1f);
    hipLaunchKernelGGL(ffq_mfma, dim3(2 * T_TOT / TB), dim3(512), 0, stream,
                       x, theta, b1, b2,
                       (const bf16x8*)w1f, (const bf16x8*)w2f, out);
}

// Round 8
// 26.787 us; speedup vs baseline: 1.0155x; 1.0155x over previous
//
#include <hip/hip_runtime.h>
#include <math.h>

typedef __attribute__((ext_vector_type(8))) short bf16x8;
typedef __attribute__((ext_vector_type(4))) float f32x4;

#define T_TOT 16384
#define E_ 256
#define FF_ 1024
#define NQ 10
#define TB 64
#define CH 256           // f per chunk
#define NCHUNK (FF_ / CH)
#define HGRAN (TB * CH)  // shorts per hs buffer (16384 = 32 KiB)

__device__ __forceinline__ unsigned short f2bf(float f) {
    unsigned u = __builtin_bit_cast(unsigned, f);
    u = (u + 0x7FFFu + ((u >> 16) & 1u)) >> 16;
    return (unsigned short)u;
}

// ---------------------------------------------------------------------------
// Prep (coalesced): bf16 MFMA B-fragments for w2 and w1^T.
// ---------------------------------------------------------------------------
__global__ __launch_bounds__(256) void ffq_prep(
    const float* __restrict__ w2, const float* __restrict__ w1,
    uint4* __restrict__ w2f, uint4* __restrict__ w1f)
{
    int id = blockIdx.x * 256 + threadIdx.x;
    if (id < 32768) {
        int n  = id >> 7;
        int k0 = (id & 127) * 8;
        const float4* s = (const float4*)(w2 + (size_t)n * FF_ + k0);
        float4 a = s[0], b = s[1];
        uint4 v;
        v.x = f2bf(a.x) | ((unsigned)f2bf(a.y) << 16);
        v.y = f2bf(a.z) | ((unsigned)f2bf(a.w) << 16);
        v.z = f2bf(b.x) | ((unsigned)f2bf(b.y) << 16);
        v.w = f2bf(b.z) | ((unsigned)f2bf(b.w) << 16);
        int idx = ((k0 >> 5) * 16 + (n >> 4)) * 64 + ((k0 >> 3) & 3) * 16 + (n & 15);
        w2f[idx] = v;
    } else if (id < 32768 + 4096) {
        int id2 = id - 32768;
        int l = id2 & 63, nt = id2 >> 6;
        int n = nt * 16 + (l & 15);
        int g = l >> 4;
        unsigned short o[8];
#pragma unroll
        for (int j = 0; j < 8; ++j) {
            int k = g * 8 + j;
            o[j] = (k < NQ) ? f2bf(w1[n * NQ + k]) : (unsigned short)0;
        }
        uint4 v;
        v.x = o[0] | ((unsigned)o[1] << 16);
        v.y = o[2] | ((unsigned)o[3] << 16);
        v.z = o[4] | ((unsigned)o[5] << 16);
        v.w = o[6] | ((unsigned)o[7] << 16);
        w1f[id2] = v;
    }
}

// ---------------------------------------------------------------------------
// Fused kernel v6 (register-pipelined):
//  - grid 512 = 256 token-tiles x 2 col-halves; 8 waves = 2 wk x 4 wc.
//  - out-phase: A depth-1 ping-pong prefetch (afA/afB), B depth-1 -> no
//    in-step ds/vm latency on the MFMA critical path.
//  - h-phase(c+1) inside same barrier region (compiler co-schedules).
//  - split-K reduce: stride-36 f32x4 LDS round-trip, conflict-free.
// ---------------------------------------------------------------------------
__global__ __launch_bounds__(512, 4) void ffq_mfma(
    const float* __restrict__ x, const float* __restrict__ theta,
    const float* __restrict__ b1, const float* __restrict__ b2,
    const bf16x8* __restrict__ w1f, const bf16x8* __restrict__ w2f,
    float* __restrict__ out)
{
    __shared__ unsigned short q_s[4 * 64 * 8];      // 4 KiB
    __shared__ unsigned short hs[2 * HGRAN];        // 64 KiB (double buffer)

    const int tid  = threadIdx.x;
    const int l    = tid & 63;
    const int wv   = tid >> 6;           // 0..7
    const int lr   = l & 15;
    const int g    = l >> 4;             // 0..3
    const int wk   = wv >> 2;            // K-half 0/1
    const int wc   = wv & 3;             // col-pair 0..3
    const int chb  = blockIdx.x & 1;     // col half 0/1
    const int tb   = (blockIdx.x >> 1) * TB;
    const int nc0  = chb * 8 + wc * 2;   // global col-tiles
    const int nc1  = nc0 + 1;

    // ---- Phase 0: threads 0..63 compute q, write B-frag granules ----
    if (tid < TB) {
        const int t = tb + tid;
        float xv[NQ];
        {
            float4 a = *(const float4*)(x + (size_t)t * E_);
            float4 b = *(const float4*)(x + (size_t)t * E_ + 4);
            float2 c = *(const float2*)(x + (size_t)t * E_ + 8);
            xv[0]=a.x; xv[1]=a.y; xv[2]=a.z; xv[3]=a.w;
            xv[4]=b.x; xv[5]=b.y; xv[6]=b.z; xv[7]=b.w;
            xv[8]=c.x; xv[9]=c.y;
        }
        float mm[NQ];
#pragma unroll
        for (int w = 0; w < NQ; ++w) mm[w] = cosf(theta[w]) * cosf(xv[w]);
        float qv[NQ];
        {
            float p = mm[0];
#pragma unroll
            for (int w = 1; w < NQ; ++w) { p *= mm[w]; qv[w] = p; }
            float p0 = mm[1];
#pragma unroll
            for (int w = 2; w < NQ; ++w) p0 *= mm[w];
            qv[0] = p0;
        }
        unsigned short qb[10];
#pragma unroll
        for (int k = 0; k < NQ; ++k) qb[k] = f2bf(qv[k]);
        uint4 s0, s1;
        s0.x = qb[0] | ((unsigned)qb[1] << 16);
        s0.y = qb[2] | ((unsigned)qb[3] << 16);
        s0.z = qb[4] | ((unsigned)qb[5] << 16);
        s0.w = qb[6] | ((unsigned)qb[7] << 16);
        s1.x = qb[8] | ((unsigned)qb[9] << 16);
        s1.y = 0; s1.z = 0; s1.w = 0;
        int tt = tid >> 4, r = tid & 15;
        uint4* base = (uint4*)q_s + tt * 64;
        base[r]      = s0;
        base[16 + r] = s1;
        base[32 + r] = make_uint4(0, 0, 0, 0);
        base[48 + r] = make_uint4(0, 0, 0, 0);
    }
    __syncthreads();

    f32x4 acc[4][2];
#pragma unroll
    for (int tt = 0; tt < 4; ++tt)
#pragma unroll
        for (int nn = 0; nn < 2; ++nn) acc[tt][nn] = (f32x4){0.f,0.f,0.f,0.f};

    // ---- h-phase macro (chunk cc -> buffer hdst); loads issued upfront ----
#define H_PHASE(cc, hdst)                                                      \
    {                                                                          \
        bf16x8 wfa = w1f[((cc) * 16 + wv * 2 + 0) * 64 + l];                   \
        bf16x8 wfb = w1f[((cc) * 16 + wv * 2 + 1) * 64 + l];                   \
        float4 bba = *(const float4*)(b1 + ((cc) * 16 + wv * 2 + 0) * 16 + g * 4); \
        float4 bbb = *(const float4*)(b1 + ((cc) * 16 + wv * 2 + 1) * 16 + g * 4); \
        bf16x8 qfr[4];                                                         \
        _Pragma("unroll")                                                      \
        for (int tt = 0; tt < 4; ++tt)                                         \
            qfr[tt] = ((const bf16x8*)q_s)[tt * 64 + l];                       \
        _Pragma("unroll")                                                      \
        for (int fi = 0; fi < 2; ++fi) {                                       \
            const int ftl = wv * 2 + fi;                                       \
            bf16x8 wf = fi ? wfb : wfa;                                        \
            float4 bb = fi ? bbb : bba;                                        \
            const int fl   = ftl * 16 + g * 4;                                 \
            const int sl   = (fl & 31) >> 3;                                   \
            const int gran = (fl >> 5) * 64 + lr + 16 * sl;                    \
            _Pragma("unroll")                                                  \
            for (int tt = 0; tt < 4; ++tt) {                                   \
                f32x4 d = {0.f, 0.f, 0.f, 0.f};                                \
                d = __builtin_amdgcn_mfma_f32_16x16x32_bf16(                   \
                        wf, qfr[tt], d, 0, 0, 0);                              \
                unsigned p0 = f2bf(fmaxf(d[0] + bb.x, 0.f))                    \
                            | ((unsigned)f2bf(fmaxf(d[1] + bb.y, 0.f)) << 16); \
                unsigned p1 = f2bf(fmaxf(d[2] + bb.z, 0.f))                    \
                            | ((unsigned)f2bf(fmaxf(d[3] + bb.w, 0.f)) << 16); \
                unsigned byteoff = (unsigned)(tt * 512 + gran) * 16u           \
                                 + (unsigned)(fl & 7) * 2u;                    \
                *(uint2*)((char*)(hdst) + byteoff) = make_uint2(p0, p1);       \
            }                                                                  \
        }                                                                      \
    }

    // ---- one out-step: MFMA on CUR (loaded last step), prefetch into NXT ----
#define OUT_STEP(CUR, NXT, J, PREF)                                            \
    {                                                                          \
        const int kk  = c * 8 + wk * 4 + (J);                                  \
        const int kkn = ((J) < 3) ? kk + 1 : ((c < NCHUNK - 1) ? kk + 5 : kk); \
        bf16x8 bn0 = w2f[(kkn * 16 + nc0) * 64 + l];                           \
        bf16x8 bn1 = w2f[(kkn * 16 + nc1) * 64 + l];                           \
        if (PREF) {                                                            \
            _Pragma("unroll")                                                  \
            for (int tt = 0; tt < 4; ++tt)                                     \
                NXT[tt] = hc[(tt * 8 + wk * 4 + (J) + 1) * 64 + l];            \
        }                                                                      \
        _Pragma("unroll")                                                      \
        for (int tt = 0; tt < 4; ++tt)                                         \
            acc[tt][0] = __builtin_amdgcn_mfma_f32_16x16x32_bf16(              \
                CUR[tt], bc0, acc[tt][0], 0, 0, 0);                            \
        _Pragma("unroll")                                                      \
        for (int tt = 0; tt < 4; ++tt)                                         \
            acc[tt][1] = __builtin_amdgcn_mfma_f32_16x16x32_bf16(              \
                CUR[tt], bc1, acc[tt][1], 0, 0, 0);                            \
        bc0 = bn0; bc1 = bn1;                                                  \
    }

    // ---- prologue: chunk 0 h-phase into buf0; init B prefetch ----
    H_PHASE(0, hs)
    bf16x8 bc0 = w2f[((wk * 4) * 16 + nc0) * 64 + l];
    bf16x8 bc1 = w2f[((wk * 4) * 16 + nc1) * 64 + l];
    __syncthreads();

    for (int c = 0; c < NCHUNK; ++c) {
        const bf16x8*   hc = (const bf16x8*)(hs + (c & 1) * HGRAN);
        unsigned short* hn = hs + ((c & 1) ^ 1) * HGRAN;

        bf16x8 afA[4], afB[4];
#pragma unroll
        for (int tt = 0; tt < 4; ++tt)
            afA[tt] = hc[(tt * 8 + wk * 4) * 64 + l];

        OUT_STEP(afA, afB, 0, 1)
        OUT_STEP(afB, afA, 1, 1)
        OUT_STEP(afA, afB, 2, 1)
        OUT_STEP(afB, afA, 3, 0)

        if (c < NCHUNK - 1) {
            H_PHASE(c + 1, hn)
        }
        __syncthreads();
    }
#undef OUT_STEP
#undef H_PHASE

    // ---- split-K reduce via LDS (stride 36 floats: 16B-aligned, clean) ----
    float* pbuf = (float*)hs;
    const int idx = wc * 64 + l;     // 0..255, shared by wk=0/1 partners
    if (wk == 1) {
#pragma unroll
        for (int tt = 0; tt < 4; ++tt) {
            *(f32x4*)&pbuf[idx * 36 + tt * 8]     = acc[tt][0];
            *(f32x4*)&pbuf[idx * 36 + tt * 8 + 4] = acc[tt][1];
        }
    }
    __syncthreads();
    if (wk == 0) {
#pragma unroll
        for (int tt = 0; tt < 4; ++tt) {
            f32x4 p0 = *(const f32x4*)&pbuf[idx * 36 + tt * 8];
            f32x4 p1 = *(const f32x4*)&pbuf[idx * 36 + tt * 8 + 4];
#pragma unroll
            for (int r = 0; r < 4; ++r) { acc[tt][0][r] += p0[r]; acc[tt][1][r] += p1[r]; }
        }

        // ---- epilogue: + b2, store fp32 ----
#pragma unroll
        for (int nn = 0; nn < 2; ++nn) {
            const int col = (nc0 + nn) * 16 + lr;
            const float bbv = b2[col];
#pragma unroll
            for (int tt = 0; tt < 4; ++tt) {
#pragma unroll
                for (int r = 0; r < 4; ++r) {
                    int tr = tb + tt * 16 + g * 4 + r;
                    out[(size_t)tr * E_ + col] = acc[tt][nn][r] + bbv;
                }
            }
        }
    }
}

extern "C" void kernel_launch(void* const* d_in, const int* in_sizes, int n_in,
                              void* d_out, int out_size, void* d_ws, size_t ws_size,
                              hipStream_t stream) {
    const float* x     = (const float*)d_in[0];
    const float* theta = (const float*)d_in[1];
    const float* w1    = (const float*)d_in[2];
    const float* b1    = (const float*)d_in[3];
    const float* w2    = (const float*)d_in[4];
    const float* b2    = (const float*)d_in[5];
    float* out = (float*)d_out;

    uint4* w2f = (uint4*)d_ws;                          // 512 KiB
    uint4* w1f = (uint4*)((char*)d_ws + 512 * 1024);    // 64 KiB

    hipLaunchKernelGGL(ffq_prep, dim3(144), dim3(256), 0, stream,
                       w2, w1, w2f, w1f);
    hipLaunchKernelGGL(ffq_mfma, dim3(2 * T_TOT / TB), dim3(512), 0, stream,
                       x, theta, b1, b2,
                       (const bf16x8*)w1f, (const bf16x8*)w2f, out);
}

// Round 9
// 26.072 us; speedup vs baseline: 1.0433x; 1.0274x over previous
//
#include <hip/hip_runtime.h>
#include <hip/hip_bf16.h>
#include <math.h>

typedef __attribute__((ext_vector_type(8))) short bf16x8;
typedef __attribute__((ext_vector_type(4))) float f32x4;

#define T_TOT 16384
#define E_ 256
#define FF_ 1024
#define NQ 10
#define TB 64
#define CH 256           // f per chunk
#define NCHUNK (FF_ / CH)
#define HGRAN (TB * CH)  // shorts per hs buffer (16384 = 32 KiB)

// paired f32->bf16 RNE via v_cvt_pk_bf16_f32 (1 VALU per 2 values)
__device__ __forceinline__ unsigned pkbf(float a, float b) {
    __hip_bfloat162 t = __float22bfloat162_rn(make_float2(a, b));
    return *(unsigned*)&t;
}

// ---------------------------------------------------------------------------
// Prep (coalesced): bf16 MFMA B-fragments for w2 and w1^T.
// ---------------------------------------------------------------------------
__global__ __launch_bounds__(256) void ffq_prep(
    const float* __restrict__ w2, const float* __restrict__ w1,
    uint4* __restrict__ w2f, uint4* __restrict__ w1f)
{
    int id = blockIdx.x * 256 + threadIdx.x;
    if (id < 32768) {
        int n  = id >> 7;
        int k0 = (id & 127) * 8;
        const float4* s = (const float4*)(w2 + (size_t)n * FF_ + k0);
        float4 a = s[0], b = s[1];
        uint4 v;
        v.x = pkbf(a.x, a.y);
        v.y = pkbf(a.z, a.w);
        v.z = pkbf(b.x, b.y);
        v.w = pkbf(b.z, b.w);
        int idx = ((k0 >> 5) * 16 + (n >> 4)) * 64 + ((k0 >> 3) & 3) * 16 + (n & 15);
        w2f[idx] = v;
    } else if (id < 32768 + 4096) {
        int id2 = id - 32768;
        int l = id2 & 63, nt = id2 >> 6;
        int n = nt * 16 + (l & 15);
        int g = l >> 4;
        float o[8];
#pragma unroll
        for (int j = 0; j < 8; ++j) {
            int k = g * 8 + j;
            o[j] = (k < NQ) ? w1[n * NQ + k] : 0.f;
        }
        uint4 v;
        v.x = pkbf(o[0], o[1]);
        v.y = pkbf(o[2], o[3]);
        v.z = pkbf(o[4], o[5]);
        v.w = pkbf(o[6], o[7]);
        w1f[id2] = v;
    }
}

// ---------------------------------------------------------------------------
// Fused kernel v7 (= v6 structure, VALU-slimmed epilogues via cvt_pk):
//  - grid 512 = 256 token-tiles x 2 col-halves; 8 waves = 2 wk x 4 wc.
//  - A depth-1 ping-pong prefetch, B depth-1 prefetch, hs double-buffered.
//  - split-K reduce via LDS, wk=0 stores.
// ---------------------------------------------------------------------------
__global__ __launch_bounds__(512, 4) void ffq_mfma(
    const float* __restrict__ x, const float* __restrict__ theta,
    const float* __restrict__ b1, const float* __restrict__ b2,
    const bf16x8* __restrict__ w1f, const bf16x8* __restrict__ w2f,
    float* __restrict__ out)
{
    __shared__ unsigned short q_s[4 * 64 * 8];      // 4 KiB
    __shared__ unsigned short hs[2 * HGRAN];        // 64 KiB (double buffer)

    const int tid  = threadIdx.x;
    const int l    = tid & 63;
    const int wv   = tid >> 6;           // 0..7
    const int lr   = l & 15;
    const int g    = l >> 4;             // 0..3
    const int wk   = wv >> 2;            // K-half 0/1
    const int wc   = wv & 3;             // col-pair 0..3
    const int chb  = blockIdx.x & 1;     // col half 0/1
    const int tb   = (blockIdx.x >> 1) * TB;
    const int nc0  = chb * 8 + wc * 2;   // global col-tiles
    const int nc1  = nc0 + 1;

    // ---- Phase 0: threads 0..63 compute q, write B-frag granules ----
    if (tid < TB) {
        const int t = tb + tid;
        float xv[NQ];
        {
            float4 a = *(const float4*)(x + (size_t)t * E_);
            float4 b = *(const float4*)(x + (size_t)t * E_ + 4);
            float2 c = *(const float2*)(x + (size_t)t * E_ + 8);
            xv[0]=a.x; xv[1]=a.y; xv[2]=a.z; xv[3]=a.w;
            xv[4]=b.x; xv[5]=b.y; xv[6]=b.z; xv[7]=b.w;
            xv[8]=c.x; xv[9]=c.y;
        }
        float mm[NQ];
#pragma unroll
        for (int w = 0; w < NQ; ++w) mm[w] = cosf(theta[w]) * cosf(xv[w]);
        float qv[NQ];
        {
            float p = mm[0];
#pragma unroll
            for (int w = 1; w < NQ; ++w) { p *= mm[w]; qv[w] = p; }
            float p0 = mm[1];
#pragma unroll
            for (int w = 2; w < NQ; ++w) p0 *= mm[w];
            qv[0] = p0;
        }
        uint4 s0, s1;
        s0.x = pkbf(qv[0], qv[1]);
        s0.y = pkbf(qv[2], qv[3]);
        s0.z = pkbf(qv[4], qv[5]);
        s0.w = pkbf(qv[6], qv[7]);
        s1.x = pkbf(qv[8], qv[9]);
        s1.y = 0; s1.z = 0; s1.w = 0;
        int tt = tid >> 4, r = tid & 15;
        uint4* base = (uint4*)q_s + tt * 64;
        base[r]      = s0;
        base[16 + r] = s1;
        base[32 + r] = make_uint4(0, 0, 0, 0);
        base[48 + r] = make_uint4(0, 0, 0, 0);
    }
    __syncthreads();

    // persistent q fragments (one LDS read, reused every chunk)
    bf16x8 qf[4];
#pragma unroll
    for (int tt = 0; tt < 4; ++tt) qf[tt] = ((const bf16x8*)q_s)[tt * 64 + l];

    f32x4 acc[4][2];
#pragma unroll
    for (int tt = 0; tt < 4; ++tt)
#pragma unroll
        for (int nn = 0; nn < 2; ++nn) acc[tt][nn] = (f32x4){0.f,0.f,0.f,0.f};

    // ---- h-phase macro (chunk cc -> buffer hdst); cvt_pk epilogue ----
#define H_PHASE(cc, hdst)                                                      \
    {                                                                          \
        bf16x8 wfa = w1f[((cc) * 16 + wv * 2 + 0) * 64 + l];                   \
        bf16x8 wfb = w1f[((cc) * 16 + wv * 2 + 1) * 64 + l];                   \
        float4 bba = *(const float4*)(b1 + ((cc) * 16 + wv * 2 + 0) * 16 + g * 4); \
        float4 bbb = *(const float4*)(b1 + ((cc) * 16 + wv * 2 + 1) * 16 + g * 4); \
        _Pragma("unroll")                                                      \
        for (int fi = 0; fi < 2; ++fi) {                                       \
            const int ftl = wv * 2 + fi;                                       \
            bf16x8 wf = fi ? wfb : wfa;                                        \
            float4 bb = fi ? bbb : bba;                                        \
            const int fl   = ftl * 16 + g * 4;                                 \
            const int sl   = (fl & 31) >> 3;                                   \
            const int gran = (fl >> 5) * 64 + lr + 16 * sl;                    \
            _Pragma("unroll")                                                  \
            for (int tt = 0; tt < 4; ++tt) {                                   \
                f32x4 d = {0.f, 0.f, 0.f, 0.f};                                \
                d = __builtin_amdgcn_mfma_f32_16x16x32_bf16(                   \
                        wf, qf[tt], d, 0, 0, 0);                               \
                unsigned p0 = pkbf(fmaxf(d[0] + bb.x, 0.f),                    \
                                   fmaxf(d[1] + bb.y, 0.f));                   \
                unsigned p1 = pkbf(fmaxf(d[2] + bb.z, 0.f),                    \
                                   fmaxf(d[3] + bb.w, 0.f));                   \
                unsigned byteoff = (unsigned)(tt * 512 + gran) * 16u           \
                                 + (unsigned)(fl & 7) * 2u;                    \
                *(uint2*)((char*)(hdst) + byteoff) = make_uint2(p0, p1);       \
            }                                                                  \
        }                                                                      \
    }

    // ---- one out-step: MFMA on CUR (loaded last step), prefetch into NXT ----
#define OUT_STEP(CUR, NXT, J, PREF)                                            \
    {                                                                          \
        const int kk  = c * 8 + wk * 4 + (J);                                  \
        const int kkn = ((J) < 3) ? kk + 1 : ((c < NCHUNK - 1) ? kk + 5 : kk); \
        bf16x8 bn0 = w2f[(kkn * 16 + nc0) * 64 + l];                           \
        bf16x8 bn1 = w2f[(kkn * 16 + nc1) * 64 + l];                           \
        if (PREF) {                                                            \
            _Pragma("unroll")                                                  \
            for (int tt = 0; tt < 4; ++tt)                                     \
                NXT[tt] = hc[(tt * 8 + wk * 4 + (J) + 1) * 64 + l];            \
        }                                                                      \
        _Pragma("unroll")                                                      \
        for (int tt = 0; tt < 4; ++tt)                                         \
            acc[tt][0] = __builtin_amdgcn_mfma_f32_16x16x32_bf16(              \
                CUR[tt], bc0, acc[tt][0], 0, 0, 0);                            \
        _Pragma("unroll")                                                      \
        for (int tt = 0; tt < 4; ++tt)                                         \
            acc[tt][1] = __builtin_amdgcn_mfma_f32_16x16x32_bf16(              \
                CUR[tt], bc1, acc[tt][1], 0, 0, 0);                            \
        bc0 = bn0; bc1 = bn1;                                                  \
    }

    // ---- prologue: chunk 0 h-phase into buf0; init B prefetch ----
    H_PHASE(0, hs)
    bf16x8 bc0 = w2f[((wk * 4) * 16 + nc0) * 64 + l];
    bf16x8 bc1 = w2f[((wk * 4) * 16 + nc1) * 64 + l];
    __syncthreads();

    for (int c = 0; c < NCHUNK; ++c) {
        const bf16x8*   hc = (const bf16x8*)(hs + (c & 1) * HGRAN);
        unsigned short* hn = hs + ((c & 1) ^ 1) * HGRAN;

        bf16x8 afA[4], afB[4];
#pragma unroll
        for (int tt = 0; tt < 4; ++tt)
            afA[tt] = hc[(tt * 8 + wk * 4) * 64 + l];

        OUT_STEP(afA, afB, 0, 1)
        OUT_STEP(afB, afA, 1, 1)
        OUT_STEP(afA, afB, 2, 1)
        OUT_STEP(afB, afA, 3, 0)

        if (c < NCHUNK - 1) {
            H_PHASE(c + 1, hn)
        }
        __syncthreads();
    }
#undef OUT_STEP
#undef H_PHASE

    // ---- split-K reduce via LDS (stride 36 floats: 16B-aligned, clean) ----
    float* pbuf = (float*)hs;
    const int idx = wc * 64 + l;     // 0..255, shared by wk=0/1 partners
    if (wk == 1) {
#pragma unroll
        for (int tt = 0; tt < 4; ++tt) {
            *(f32x4*)&pbuf[idx * 36 + tt * 8]     = acc[tt][0];
            *(f32x4*)&pbuf[idx * 36 + tt * 8 + 4] = acc[tt][1];
        }
    }
    __syncthreads();
    if (wk == 0) {
#pragma unroll
        for (int tt = 0; tt < 4; ++tt) {
            f32x4 p0 = *(const f32x4*)&pbuf[idx * 36 + tt * 8];
            f32x4 p1 = *(const f32x4*)&pbuf[idx * 36 + tt * 8 + 4];
#pragma unroll
            for (int r = 0; r < 4; ++r) { acc[tt][0][r] += p0[r]; acc[tt][1][r] += p1[r]; }
        }

        // ---- epilogue: + b2, store fp32 ----
#pragma unroll
        for (int nn = 0; nn < 2; ++nn) {
            const int col = (nc0 + nn) * 16 + lr;
            const float bbv = b2[col];
#pragma unroll
            for (int tt = 0; tt < 4; ++tt) {
#pragma unroll
                for (int r = 0; r < 4; ++r) {
                    int tr = tb + tt * 16 + g * 4 + r;
                    out[(size_t)tr * E_ + col] = acc[tt][nn][r] + bbv;
                }
            }
        }
    }
}

extern "C" void kernel_launch(void* const* d_in, const int* in_sizes, int n_in,
                              void* d_out, int out_size, void* d_ws, size_t ws_size,
                              hipStream_t stream) {
    const float* x     = (const float*)d_in[0];
    const float* theta = (const float*)d_in[1];
    const float* w1    = (const float*)d_in[2];
    const float* b1    = (const float*)d_in[3];
    const float* w2    = (const float*)d_in[4];
    const float* b2    = (const float*)d_in[5];
    float* out = (float*)d_out;

    uint4* w2f = (uint4*)d_ws;                          // 512 KiB
    uint4* w1f = (uint4*)((char*)d_ws + 512 * 1024);    // 64 KiB

    hipLaunchKernelGGL(ffq_prep, dim3(144), dim3(256), 0, stream,
                       w2, w1, w2f, w1f);
    hipLaunchKernelGGL(ffq_mfma, dim3(2 * T_TOT / TB), dim3(512), 0, stream,
                       x, theta, b1, b2,
                       (const bf16x8*)w1f, (const bf16x8*)w2f, out);
}